// Round 1
// baseline (510.639 us; speedup 1.0000x reference)
//
#include <hip/hip_runtime.h>

// Problem constants
#define B_    2
#define S_    2048
#define HID_  1536
#define NH_   12
#define NKV_  2
#define HD_   128
#define GRP_  6
#define NQKV_ 2048

// converted-input region layout (element offsets)
#define CV_HS  0
#define CV_QW  6291456
#define CV_KW  8650752
#define CV_VW  9043968
#define CV_OW  9437184
#define CV_TOT 11796480

typedef __attribute__((ext_vector_type(8))) short bf16x8;
typedef __attribute__((ext_vector_type(4))) float f32x4;

__device__ __forceinline__ float bf2f(unsigned short u) {
    union { unsigned int i; float f; } v; v.i = ((unsigned int)u) << 16; return v.f;
}
__device__ __forceinline__ unsigned short f2bf(float f) {
    union { float f; unsigned int i; } v; v.f = f;
    unsigned int r = v.i + 0x7fffu + ((v.i >> 16) & 1u);  // RNE
    return (unsigned short)(r >> 16);
}

__device__ __forceinline__ void gload_lds16(const unsigned short* g, unsigned short* l) {
    __builtin_amdgcn_global_load_lds(
        (const __attribute__((address_space(1))) void*)g,
        (__attribute__((address_space(3))) void*)l, 16, 0, 0);
}

// ---------------------------------------------------------------------------
// dtype detection: if hidden_states is bf16, even-indexed ushorts are bf16
// values of N(0,1) data (exponent byte near 127). flag: 0 = bf16, 1 = f32.
// ---------------------------------------------------------------------------
__global__ void detect_dtype(const unsigned short* __restrict__ hs, int* __restrict__ flag) {
    const int i = threadIdx.x;                  // 64 threads
    const unsigned short u = hs[2 * i];
    const int e = (u >> 7) & 0xFF;
    const bool sane = (e >= 96 && e <= 143);    // |x| in [2^-31, 2^16]
    const unsigned long long m = __ballot(sane);
    if (i == 0) flag[0] = (__popcll(m) < 32) ? 1 : 0;
}

// 8 elements per thread; all region boundaries are multiples of 8.
__global__ __launch_bounds__(256) void convert_inputs(
    const void* __restrict__ hs, const void* __restrict__ qw,
    const void* __restrict__ kw, const void* __restrict__ vw,
    const void* __restrict__ ow, const int* __restrict__ flag,
    unsigned short* __restrict__ dst)
{
    const size_t idx = ((size_t)blockIdx.x * 256 + threadIdx.x) * 8;
    if (idx >= CV_TOT) return;
    const void* p; size_t j;
    if (idx < CV_QW)      { p = hs; j = idx; }
    else if (idx < CV_KW) { p = qw; j = idx - CV_QW; }
    else if (idx < CV_VW) { p = kw; j = idx - CV_KW; }
    else if (idx < CV_OW) { p = vw; j = idx - CV_VW; }
    else                  { p = ow; j = idx - CV_OW; }
    if (flag[0]) {
        const float* src = (const float*)p + j;
        const float4 f0 = *(const float4*)(src);
        const float4 f1 = *(const float4*)(src + 4);
        uint4 o;
        o.x = (unsigned int)f2bf(f0.x) | ((unsigned int)f2bf(f0.y) << 16);
        o.y = (unsigned int)f2bf(f0.z) | ((unsigned int)f2bf(f0.w) << 16);
        o.z = (unsigned int)f2bf(f1.x) | ((unsigned int)f2bf(f1.y) << 16);
        o.w = (unsigned int)f2bf(f1.z) | ((unsigned int)f2bf(f1.w) << 16);
        *(uint4*)(dst + idx) = o;
    } else {
        *(uint4*)(dst + idx) = *(const uint4*)((const unsigned short*)p + j);
    }
}

// ---------------------------------------------------------------------------
// GEMM QKV: C[m,n] = sum_k A[m,k]*W[n,k] + bias. m97 structure.
// ---------------------------------------------------------------------------
__global__ __launch_bounds__(256) void gemm_qkv(
    const unsigned short* __restrict__ A,     // bf16 hidden [4096,1536]
    const unsigned short* __restrict__ Wall,  // bf16 region base (qw/kw/vw)
    const void* __restrict__ qb, const void* __restrict__ kb,
    const void* __restrict__ vb, const int* __restrict__ flag,
    unsigned short* __restrict__ C)           // [4096,2048] bf16
{
    __shared__ unsigned short As[128 * 32];
    __shared__ unsigned short Ws[128 * 32];
    const int tid = threadIdx.x;
    const int w = tid >> 6, lane = tid & 63, quad = lane >> 4, l16 = lane & 15;
    const int wr = w >> 1, wc = w & 1;
    const int n0 = blockIdx.x * 128;
    const int m0 = blockIdx.y * 128;
    const int flg = flag[0];

    const unsigned short* Wp; const void* bias; int boff;
    if (n0 < 1536)      { Wp = Wall + CV_QW + (size_t)n0 * HID_;          bias = qb; boff = n0; }
    else if (n0 < 1792) { Wp = Wall + CV_KW + (size_t)(n0 - 1536) * HID_; bias = kb; boff = n0 - 1536; }
    else                { Wp = Wall + CV_VW + (size_t)(n0 - 1792) * HID_; bias = vb; boff = n0 - 1792; }

    f32x4 acc[4][4];
#pragma unroll
    for (int i = 0; i < 4; i++)
#pragma unroll
        for (int j = 0; j < 4; j++) acc[i][j] = (f32x4)0.0f;

    const int c0 = w * 64, c1 = 256 + w * 64;
    const int ca = c0 + lane, cb = c1 + lane;
    const int rA0 = ca >> 2, pA0 = (ca & 3) * 8;
    const int rA1 = cb >> 2, pA1 = (cb & 3) * 8;

    for (int kt = 0; kt < HID_ / 32; ++kt) {
        const int k0 = kt * 32;
        __syncthreads();
        gload_lds16(A  + (size_t)(m0 + rA0) * HID_ + k0 + pA0, &As[c0 * 8]);
        gload_lds16(A  + (size_t)(m0 + rA1) * HID_ + k0 + pA1, &As[c1 * 8]);
        gload_lds16(Wp + (size_t)rA0 * HID_ + k0 + pA0, &Ws[c0 * 8]);
        gload_lds16(Wp + (size_t)rA1 * HID_ + k0 + pA1, &Ws[c1 * 8]);
        __syncthreads();

        bf16x8 a[4], b[4];
#pragma unroll
        for (int mi = 0; mi < 4; mi++)
            a[mi] = *(const bf16x8*)&As[(wr * 64 + mi * 16 + l16) * 32 + quad * 8];
#pragma unroll
        for (int ni = 0; ni < 4; ni++)
            b[ni] = *(const bf16x8*)&Ws[(wc * 64 + ni * 16 + l16) * 32 + quad * 8];
#pragma unroll
        for (int mi = 0; mi < 4; mi++)
#pragma unroll
            for (int ni = 0; ni < 4; ni++)
                acc[mi][ni] = __builtin_amdgcn_mfma_f32_16x16x32_bf16(a[mi], b[ni], acc[mi][ni], 0, 0, 0);
    }

#pragma unroll
    for (int mi = 0; mi < 4; mi++) {
        const int row = m0 + wr * 64 + mi * 16 + quad * 4;
#pragma unroll
        for (int ni = 0; ni < 4; ni++) {
            const int cl = wc * 64 + ni * 16 + l16;
            const float bv = flg ? ((const float*)bias)[boff + cl]
                                 : bf2f(((const unsigned short*)bias)[boff + cl]);
#pragma unroll
            for (int r = 0; r < 4; r++)
                C[(size_t)(row + r) * NQKV_ + n0 + cl] = f2bf(acc[mi][ni][r] + bv);
        }
    }
}

__global__ __launch_bounds__(256) void gemm_o(
    const unsigned short* __restrict__ A,   // attn_out [4096,1536] bf16
    const unsigned short* __restrict__ W,   // o_w bf16 [1536,1536]
    const int* __restrict__ flag,
    void* __restrict__ C)                   // out [4096,1536] bf16 or f32
{
    __shared__ unsigned short As[128 * 32];
    __shared__ unsigned short Ws[128 * 32];
    const int tid = threadIdx.x;
    const int w = tid >> 6, lane = tid & 63, quad = lane >> 4, l16 = lane & 15;
    const int wr = w >> 1, wc = w & 1;
    const int n0 = blockIdx.x * 128;
    const int m0 = blockIdx.y * 128;
    const int flg = flag[0];
    const unsigned short* Wp = W + (size_t)n0 * HID_;

    f32x4 acc[4][4];
#pragma unroll
    for (int i = 0; i < 4; i++)
#pragma unroll
        for (int j = 0; j < 4; j++) acc[i][j] = (f32x4)0.0f;

    const int c0 = w * 64, c1 = 256 + w * 64;
    const int ca = c0 + lane, cb = c1 + lane;
    const int rA0 = ca >> 2, pA0 = (ca & 3) * 8;
    const int rA1 = cb >> 2, pA1 = (cb & 3) * 8;

    for (int kt = 0; kt < HID_ / 32; ++kt) {
        const int k0 = kt * 32;
        __syncthreads();
        gload_lds16(A  + (size_t)(m0 + rA0) * HID_ + k0 + pA0, &As[c0 * 8]);
        gload_lds16(A  + (size_t)(m0 + rA1) * HID_ + k0 + pA1, &As[c1 * 8]);
        gload_lds16(Wp + (size_t)rA0 * HID_ + k0 + pA0, &Ws[c0 * 8]);
        gload_lds16(Wp + (size_t)rA1 * HID_ + k0 + pA1, &Ws[c1 * 8]);
        __syncthreads();

        bf16x8 a[4], b[4];
#pragma unroll
        for (int mi = 0; mi < 4; mi++)
            a[mi] = *(const bf16x8*)&As[(wr * 64 + mi * 16 + l16) * 32 + quad * 8];
#pragma unroll
        for (int ni = 0; ni < 4; ni++)
            b[ni] = *(const bf16x8*)&Ws[(wc * 64 + ni * 16 + l16) * 32 + quad * 8];
#pragma unroll
        for (int mi = 0; mi < 4; mi++)
#pragma unroll
            for (int ni = 0; ni < 4; ni++)
                acc[mi][ni] = __builtin_amdgcn_mfma_f32_16x16x32_bf16(a[mi], b[ni], acc[mi][ni], 0, 0, 0);
    }

#pragma unroll
    for (int mi = 0; mi < 4; mi++) {
        const int row = m0 + wr * 64 + mi * 16 + quad * 4;
#pragma unroll
        for (int ni = 0; ni < 4; ni++) {
            const int col = n0 + wc * 64 + ni * 16 + l16;
#pragma unroll
            for (int r = 0; r < 4; r++) {
                const size_t off = (size_t)(row + r) * HID_ + col;
                if (flg) ((float*)C)[off] = acc[mi][ni][r];
                else ((unsigned short*)C)[off] = f2bf(acc[mi][ni][r]);
            }
        }
    }
}

// ---------------------------------------------------------------------------
// mrope + scatter (cos/sin read flag-adaptively from original inputs)
// ---------------------------------------------------------------------------
__global__ __launch_bounds__(256) void rope_scatter(
    const unsigned short* __restrict__ Cqkv,
    const void* __restrict__ cosp, const void* __restrict__ sinp,
    const int* __restrict__ flag,
    unsigned short* __restrict__ Q,           // [B,NH,S,HD]
    unsigned short* __restrict__ K,           // [B,NKV,S,HD]
    unsigned short* __restrict__ Vt)          // [B,NKV,HD,S]
{
    const int idx = blockIdx.x * 256 + threadIdx.x;
    const int m = idx >> 11, col = idx & 2047;
    const int b = m >> 11, s = m & 2047;
    const unsigned short raw = Cqkv[(size_t)m * NQKV_ + col];
    if (col < 1792) {
        const int d = col & 127;
        const int dd = d & 63;
        const int axis = dd < 16 ? 0 : (dd < 40 ? 1 : 2);
        const size_t cidx = (((size_t)axis * B_ + b) * S_ + s) * HD_ + d;
        const int flg = flag[0];
        const float cs = flg ? ((const float*)cosp)[cidx] : bf2f(((const unsigned short*)cosp)[cidx]);
        const float sn = flg ? ((const float*)sinp)[cidx] : bf2f(((const unsigned short*)sinp)[cidx]);
        const float x  = bf2f(raw);
        const float xp = bf2f(Cqkv[(size_t)m * NQKV_ + (col ^ 64)]);
        float y = (d < 64) ? (x * cs - xp * sn) : (x * cs + xp * sn);
        if (col < 1536) {
            const int h = col >> 7;
            y *= 0.088388347648318447f;   // 1/sqrt(128) folded into Q
            Q[(((size_t)b * NH_ + h) * S_ + s) * HD_ + d] = f2bf(y);
        } else {
            const int kv = (col - 1536) >> 7;
            K[(((size_t)b * NKV_ + kv) * S_ + s) * HD_ + d] = f2bf(y);
        }
    } else {
        const int cv = col - 1792;
        const int kv = cv >> 7, d = cv & 127;
        Vt[(((size_t)b * NKV_ + kv) * HD_ + d) * S_ + s] = raw;
    }
}

// ---------------------------------------------------------------------------
// Flash attention, causal, q-tile 64 / k-tile 64, 4 waves x 16 q-rows.
// v2: Q in registers (no Qs LDS -> 45056 B LDS -> 3 blocks/CU, all 768
// blocks co-resident); T14 async staging (prefetch t+1 K/V into regs during
// compute of t); 2 barriers/tile (Ps is wave-private); setprio around MFMA;
// qt-descending launch order (LPT insurance).
// ---------------------------------------------------------------------------
#define LOADKV(K0)                                                                        \
    do {                                                                                  \
        _Pragma("unroll")                                                                 \
        for (int i = 0; i < 4; i++)                                                       \
            kreg[i] = *(const uint4*)(Kp + (size_t)((K0) + i * 16 + krow) * HD_ + kpart); \
        _Pragma("unroll")                                                                 \
        for (int i = 0; i < 4; i++)                                                       \
            vreg[i] = *(const uint4*)(Vp + (size_t)(i * 32 + vrow) * S_ + (K0) + vpart);  \
    } while (0)

__global__ __launch_bounds__(256, 3) void attn_fwd(
    const unsigned short* __restrict__ Q,
    const unsigned short* __restrict__ K,
    const unsigned short* __restrict__ Vt,
    unsigned short* __restrict__ Aout)   // [4096, 1536]
{
    __shared__ unsigned short Ks[64][136];
    __shared__ unsigned short Vs[128][72];
    __shared__ unsigned short Ps[4][16][72];

    const int tid = threadIdx.x;
    const int w = tid >> 6, lane = tid & 63, quad = lane >> 4, l16 = lane & 15;
    const int bid = blockIdx.x;
    const int qt = 31 - (bid & 31);          // big tiles launch first
    const int h  = (bid >> 5) % NH_;
    const int b  = bid / (32 * NH_);
    const int kvh = h / GRP_;
    const int q0 = qt * 64;

    const unsigned short* Qp = Q  + (((size_t)b * NH_ + h) * S_ + q0) * HD_;
    const unsigned short* Kp = K  + ((size_t)b * NKV_ + kvh) * S_ * HD_;
    const unsigned short* Vp = Vt + ((size_t)b * NKV_ + kvh) * HD_ * S_;

    // Q fragments straight to registers (each wave reads only its 16 rows)
    bf16x8 aq[4];
    {
        const unsigned short* qr = Qp + (size_t)(w * 16 + l16) * HD_ + quad * 8;
#pragma unroll
        for (int ks = 0; ks < 4; ks++)
            aq[ks] = *(const bf16x8*)(qr + ks * 32);
    }

    // staging registers + per-thread staging coordinates
    uint4 kreg[4], vreg[4];
    const int krow = tid >> 4, kpart = (tid & 15) * 8;
    const int vrow = tid >> 3, vpart = (tid & 7) * 8;

    f32x4 O[8];
#pragma unroll
    for (int i = 0; i < 8; i++) O[i] = (f32x4)0.0f;
    float m_st[4] = {-1e30f, -1e30f, -1e30f, -1e30f};
    float l_st[4] = {0.f, 0.f, 0.f, 0.f};

    const int nkt = qt + 1;
    LOADKV(0);
    for (int t = 0; t < nkt; t++) {
        const int k0 = t * 64;
        __syncthreads();                     // prev-tile LDS readers done
#pragma unroll
        for (int i = 0; i < 4; i++) *(uint4*)&Ks[i * 16 + krow][kpart] = kreg[i];
#pragma unroll
        for (int i = 0; i < 4; i++) *(uint4*)&Vs[i * 32 + vrow][vpart] = vreg[i];
        __syncthreads();                     // tile t staged

        if (t + 1 < nkt) LOADKV((t + 1) * 64);   // prefetch hides under compute

        f32x4 Sf[4];
#pragma unroll
        for (int i = 0; i < 4; i++) Sf[i] = (f32x4)0.0f;
        __builtin_amdgcn_s_setprio(1);
#pragma unroll
        for (int ks = 0; ks < 4; ks++) {
#pragma unroll
            for (int ni = 0; ni < 4; ni++) {
                bf16x8 bk = *(const bf16x8*)&Ks[ni * 16 + l16][ks * 32 + quad * 8];
                Sf[ni] = __builtin_amdgcn_mfma_f32_16x16x32_bf16(aq[ks], bk, Sf[ni], 0, 0, 0);
            }
        }
        __builtin_amdgcn_s_setprio(0);

        if (t == nkt - 1) {
#pragma unroll
            for (int ni = 0; ni < 4; ni++)
#pragma unroll
                for (int r = 0; r < 4; r++) {
                    const int kk = k0 + ni * 16 + l16;
                    const int qq = q0 + w * 16 + quad * 4 + r;
                    if (kk > qq) Sf[ni][r] = -1e9f;
                }
        }

        float alpha[4];
#pragma unroll
        for (int r = 0; r < 4; r++) {
            float mx = fmaxf(fmaxf(Sf[0][r], Sf[1][r]), fmaxf(Sf[2][r], Sf[3][r]));
#pragma unroll
            for (int sh = 1; sh < 16; sh <<= 1) mx = fmaxf(mx, __shfl_xor(mx, sh, 64));
            const float mn = fmaxf(m_st[r], mx);
            alpha[r] = __expf(m_st[r] - mn);
            m_st[r] = mn;
            float ps = 0.f;
#pragma unroll
            for (int ni = 0; ni < 4; ni++) {
                const float p = __expf(Sf[ni][r] - mn);
                Sf[ni][r] = p;
                ps += p;
            }
#pragma unroll
            for (int sh = 1; sh < 16; sh <<= 1) ps += __shfl_xor(ps, sh, 64);
            l_st[r] = l_st[r] * alpha[r] + ps;
        }
#pragma unroll
        for (int di = 0; di < 8; di++)
#pragma unroll
            for (int r = 0; r < 4; r++) O[di][r] *= alpha[r];

        // Ps is per-wave private: no block barrier needed, compiler inserts
        // the lgkmcnt wait for the write->read dependency.
#pragma unroll
        for (int ni = 0; ni < 4; ni++)
#pragma unroll
            for (int r = 0; r < 4; r++)
                Ps[w][quad * 4 + r][ni * 16 + l16] = f2bf(Sf[ni][r]);

        __builtin_amdgcn_s_setprio(1);
#pragma unroll
        for (int ks = 0; ks < 2; ks++) {
            bf16x8 ap = *(const bf16x8*)&Ps[w][l16][ks * 32 + quad * 8];
#pragma unroll
            for (int di = 0; di < 8; di++) {
                bf16x8 bv = *(const bf16x8*)&Vs[di * 16 + l16][ks * 32 + quad * 8];
                O[di] = __builtin_amdgcn_mfma_f32_16x16x32_bf16(ap, bv, O[di], 0, 0, 0);
            }
        }
        __builtin_amdgcn_s_setprio(0);
    }

#pragma unroll
    for (int di = 0; di < 8; di++) {
        const int d = di * 16 + l16;
#pragma unroll
        for (int r = 0; r < 4; r++) {
            const int qrow = q0 + w * 16 + quad * 4 + r;
            const float v = O[di][r] / l_st[r];
            Aout[((size_t)b * S_ + qrow) * HID_ + h * HD_ + d] = f2bf(v);
        }
    }
}

extern "C" void kernel_launch(void* const* d_in, const int* in_sizes, int n_in,
                              void* d_out, int out_size, void* d_ws, size_t ws_size,
                              hipStream_t stream) {
    const void* hs   = d_in[0];
    const void* qw   = d_in[1];
    const void* qb   = d_in[2];
    const void* kw   = d_in[3];
    const void* kb   = d_in[4];
    const void* vw   = d_in[5];
    const void* vb   = d_in[6];
    const void* ow   = d_in[7];
    const void* cosp = d_in[8];
    const void* sinp = d_in[9];

    int* flag = (int*)d_ws;                                       // 16 shorts reserved
    unsigned short* conv = (unsigned short*)d_ws + 16;            // CV_TOT = 11796480
    unsigned short* Cqkv = conv + CV_TOT;                         // 8388608
    unsigned short* Qb   = Cqkv + (size_t)8388608;                // 6291456
    unsigned short* Kb   = Qb + (size_t)6291456;                  // 1048576
    unsigned short* Vtb  = Kb + (size_t)1048576;                  // 1048576
    unsigned short* Ao   = Cqkv;                                  // reuse (dead after rope)

    detect_dtype<<<1, 64, 0, stream>>>((const unsigned short*)hs, flag);
    convert_inputs<<<(CV_TOT / 8 + 255) / 256, 256, 0, stream>>>(hs, qw, kw, vw, ow, flag, conv);
    gemm_qkv<<<dim3(16, 32), 256, 0, stream>>>(conv + CV_HS, conv, qb, kb, vb, flag, Cqkv);
    rope_scatter<<<dim3((4096 * 2048) / 256), 256, 0, stream>>>(Cqkv, cosp, sinp, flag, Qb, Kb, Vtb);
    attn_fwd<<<dim3(2 * 12 * 32), 256, 0, stream>>>(Qb, Kb, Vtb, Ao);
    gemm_o<<<dim3(12, 32), 256, 0, stream>>>(Ao, conv + CV_OW, flag, d_out);
}

// Round 2
// 347.245 us; speedup vs baseline: 1.4705x; 1.4705x over previous
//
#include <hip/hip_runtime.h>

// Problem constants
#define B_    2
#define S_    2048
#define HID_  1536
#define NH_   12
#define NKV_  2
#define HD_   128
#define GRP_  6
#define NQKV_ 2048

// converted-input region layout (element offsets)
#define CV_HS  0
#define CV_QW  6291456
#define CV_KW  8650752
#define CV_VW  9043968
#define CV_OW  9437184
#define CV_TOT 11796480

typedef __attribute__((ext_vector_type(8))) short bf16x8;
typedef __attribute__((ext_vector_type(4))) float f32x4;

__device__ __forceinline__ float bf2f(unsigned short u) {
    union { unsigned int i; float f; } v; v.i = ((unsigned int)u) << 16; return v.f;
}
__device__ __forceinline__ unsigned short f2bf(float f) {
    union { float f; unsigned int i; } v; v.f = f;
    unsigned int r = v.i + 0x7fffu + ((v.i >> 16) & 1u);  // RNE
    return (unsigned short)(r >> 16);
}

__device__ __forceinline__ void gload_lds16(const unsigned short* g, unsigned short* l) {
    __builtin_amdgcn_global_load_lds(
        (const __attribute__((address_space(1))) void*)g,
        (__attribute__((address_space(3))) void*)l, 16, 0, 0);
}
__device__ __forceinline__ void gload_lds16b(const char* g, char* l) {
    __builtin_amdgcn_global_load_lds(
        (const __attribute__((address_space(1))) void*)g,
        (__attribute__((address_space(3))) void*)l, 16, 0, 0);
}

// ---------------------------------------------------------------------------
// dtype detection: if hidden_states is bf16, even-indexed ushorts are bf16
// values of N(0,1) data (exponent byte near 127). flag: 0 = bf16, 1 = f32.
// ---------------------------------------------------------------------------
__global__ void detect_dtype(const unsigned short* __restrict__ hs, int* __restrict__ flag) {
    const int i = threadIdx.x;                  // 64 threads
    const unsigned short u = hs[2 * i];
    const int e = (u >> 7) & 0xFF;
    const bool sane = (e >= 96 && e <= 143);    // |x| in [2^-31, 2^16]
    const unsigned long long m = __ballot(sane);
    if (i == 0) flag[0] = (__popcll(m) < 32) ? 1 : 0;
}

// 8 elements per thread; all region boundaries are multiples of 8.
__global__ __launch_bounds__(256) void convert_inputs(
    const void* __restrict__ hs, const void* __restrict__ qw,
    const void* __restrict__ kw, const void* __restrict__ vw,
    const void* __restrict__ ow, const int* __restrict__ flag,
    unsigned short* __restrict__ dst)
{
    const size_t idx = ((size_t)blockIdx.x * 256 + threadIdx.x) * 8;
    if (idx >= CV_TOT) return;
    const void* p; size_t j;
    if (idx < CV_QW)      { p = hs; j = idx; }
    else if (idx < CV_KW) { p = qw; j = idx - CV_QW; }
    else if (idx < CV_VW) { p = kw; j = idx - CV_KW; }
    else if (idx < CV_OW) { p = vw; j = idx - CV_VW; }
    else                  { p = ow; j = idx - CV_OW; }
    if (flag[0]) {
        const float* src = (const float*)p + j;
        const float4 f0 = *(const float4*)(src);
        const float4 f1 = *(const float4*)(src + 4);
        uint4 o;
        o.x = (unsigned int)f2bf(f0.x) | ((unsigned int)f2bf(f0.y) << 16);
        o.y = (unsigned int)f2bf(f0.z) | ((unsigned int)f2bf(f0.w) << 16);
        o.z = (unsigned int)f2bf(f1.x) | ((unsigned int)f2bf(f1.y) << 16);
        o.w = (unsigned int)f2bf(f1.z) | ((unsigned int)f2bf(f1.w) << 16);
        *(uint4*)(dst + idx) = o;
    } else {
        *(uint4*)(dst + idx) = *(const uint4*)((const unsigned short*)p + j);
    }
}

// ---------------------------------------------------------------------------
// GEMM QKV: C[m,n] = sum_k A[m,k]*W[n,k] + bias. m97 structure.
// ---------------------------------------------------------------------------
__global__ __launch_bounds__(256) void gemm_qkv(
    const unsigned short* __restrict__ A,     // bf16 hidden [4096,1536]
    const unsigned short* __restrict__ Wall,  // bf16 region base (qw/kw/vw)
    const void* __restrict__ qb, const void* __restrict__ kb,
    const void* __restrict__ vb, const int* __restrict__ flag,
    unsigned short* __restrict__ C)           // [4096,2048] bf16
{
    __shared__ unsigned short As[128 * 32];
    __shared__ unsigned short Ws[128 * 32];
    const int tid = threadIdx.x;
    const int w = tid >> 6, lane = tid & 63, quad = lane >> 4, l16 = lane & 15;
    const int wr = w >> 1, wc = w & 1;
    const int n0 = blockIdx.x * 128;
    const int m0 = blockIdx.y * 128;
    const int flg = flag[0];

    const unsigned short* Wp; const void* bias; int boff;
    if (n0 < 1536)      { Wp = Wall + CV_QW + (size_t)n0 * HID_;          bias = qb; boff = n0; }
    else if (n0 < 1792) { Wp = Wall + CV_KW + (size_t)(n0 - 1536) * HID_; bias = kb; boff = n0 - 1536; }
    else                { Wp = Wall + CV_VW + (size_t)(n0 - 1792) * HID_; bias = vb; boff = n0 - 1792; }

    f32x4 acc[4][4];
#pragma unroll
    for (int i = 0; i < 4; i++)
#pragma unroll
        for (int j = 0; j < 4; j++) acc[i][j] = (f32x4)0.0f;

    const int c0 = w * 64, c1 = 256 + w * 64;
    const int ca = c0 + lane, cb = c1 + lane;
    const int rA0 = ca >> 2, pA0 = (ca & 3) * 8;
    const int rA1 = cb >> 2, pA1 = (cb & 3) * 8;

    for (int kt = 0; kt < HID_ / 32; ++kt) {
        const int k0 = kt * 32;
        __syncthreads();
        gload_lds16(A  + (size_t)(m0 + rA0) * HID_ + k0 + pA0, &As[c0 * 8]);
        gload_lds16(A  + (size_t)(m0 + rA1) * HID_ + k0 + pA1, &As[c1 * 8]);
        gload_lds16(Wp + (size_t)rA0 * HID_ + k0 + pA0, &Ws[c0 * 8]);
        gload_lds16(Wp + (size_t)rA1 * HID_ + k0 + pA1, &Ws[c1 * 8]);
        __syncthreads();

        bf16x8 a[4], b[4];
#pragma unroll
        for (int mi = 0; mi < 4; mi++)
            a[mi] = *(const bf16x8*)&As[(wr * 64 + mi * 16 + l16) * 32 + quad * 8];
#pragma unroll
        for (int ni = 0; ni < 4; ni++)
            b[ni] = *(const bf16x8*)&Ws[(wc * 64 + ni * 16 + l16) * 32 + quad * 8];
#pragma unroll
        for (int mi = 0; mi < 4; mi++)
#pragma unroll
            for (int ni = 0; ni < 4; ni++)
                acc[mi][ni] = __builtin_amdgcn_mfma_f32_16x16x32_bf16(a[mi], b[ni], acc[mi][ni], 0, 0, 0);
    }

#pragma unroll
    for (int mi = 0; mi < 4; mi++) {
        const int row = m0 + wr * 64 + mi * 16 + quad * 4;
#pragma unroll
        for (int ni = 0; ni < 4; ni++) {
            const int cl = wc * 64 + ni * 16 + l16;
            const float bv = flg ? ((const float*)bias)[boff + cl]
                                 : bf2f(((const unsigned short*)bias)[boff + cl]);
#pragma unroll
            for (int r = 0; r < 4; r++)
                C[(size_t)(row + r) * NQKV_ + n0 + cl] = f2bf(acc[mi][ni][r] + bv);
        }
    }
}

__global__ __launch_bounds__(256) void gemm_o(
    const unsigned short* __restrict__ A,   // attn_out [4096,1536] bf16
    const unsigned short* __restrict__ W,   // o_w bf16 [1536,1536]
    const int* __restrict__ flag,
    void* __restrict__ C)                   // out [4096,1536] bf16 or f32
{
    __shared__ unsigned short As[128 * 32];
    __shared__ unsigned short Ws[128 * 32];
    const int tid = threadIdx.x;
    const int w = tid >> 6, lane = tid & 63, quad = lane >> 4, l16 = lane & 15;
    const int wr = w >> 1, wc = w & 1;
    const int n0 = blockIdx.x * 128;
    const int m0 = blockIdx.y * 128;
    const int flg = flag[0];
    const unsigned short* Wp = W + (size_t)n0 * HID_;

    f32x4 acc[4][4];
#pragma unroll
    for (int i = 0; i < 4; i++)
#pragma unroll
        for (int j = 0; j < 4; j++) acc[i][j] = (f32x4)0.0f;

    const int c0 = w * 64, c1 = 256 + w * 64;
    const int ca = c0 + lane, cb = c1 + lane;
    const int rA0 = ca >> 2, pA0 = (ca & 3) * 8;
    const int rA1 = cb >> 2, pA1 = (cb & 3) * 8;

    for (int kt = 0; kt < HID_ / 32; ++kt) {
        const int k0 = kt * 32;
        __syncthreads();
        gload_lds16(A  + (size_t)(m0 + rA0) * HID_ + k0 + pA0, &As[c0 * 8]);
        gload_lds16(A  + (size_t)(m0 + rA1) * HID_ + k0 + pA1, &As[c1 * 8]);
        gload_lds16(Wp + (size_t)rA0 * HID_ + k0 + pA0, &Ws[c0 * 8]);
        gload_lds16(Wp + (size_t)rA1 * HID_ + k0 + pA1, &Ws[c1 * 8]);
        __syncthreads();

        bf16x8 a[4], b[4];
#pragma unroll
        for (int mi = 0; mi < 4; mi++)
            a[mi] = *(const bf16x8*)&As[(wr * 64 + mi * 16 + l16) * 32 + quad * 8];
#pragma unroll
        for (int ni = 0; ni < 4; ni++)
            b[ni] = *(const bf16x8*)&Ws[(wc * 64 + ni * 16 + l16) * 32 + quad * 8];
#pragma unroll
        for (int mi = 0; mi < 4; mi++)
#pragma unroll
            for (int ni = 0; ni < 4; ni++)
                acc[mi][ni] = __builtin_amdgcn_mfma_f32_16x16x32_bf16(a[mi], b[ni], acc[mi][ni], 0, 0, 0);
    }

#pragma unroll
    for (int mi = 0; mi < 4; mi++) {
        const int row = m0 + wr * 64 + mi * 16 + quad * 4;
#pragma unroll
        for (int ni = 0; ni < 4; ni++) {
            const int col = n0 + wc * 64 + ni * 16 + l16;
#pragma unroll
            for (int r = 0; r < 4; r++) {
                const size_t off = (size_t)(row + r) * HID_ + col;
                if (flg) ((float*)C)[off] = acc[mi][ni][r];
                else ((unsigned short*)C)[off] = f2bf(acc[mi][ni][r]);
            }
        }
    }
}

// ---------------------------------------------------------------------------
// mrope + scatter (cos/sin read flag-adaptively from original inputs)
// ---------------------------------------------------------------------------
__global__ __launch_bounds__(256) void rope_scatter(
    const unsigned short* __restrict__ Cqkv,
    const void* __restrict__ cosp, const void* __restrict__ sinp,
    const int* __restrict__ flag,
    unsigned short* __restrict__ Q,           // [B,NH,S,HD]
    unsigned short* __restrict__ K,           // [B,NKV,S,HD]
    unsigned short* __restrict__ Vt)          // [B,NKV,HD,S]
{
    const int idx = blockIdx.x * 256 + threadIdx.x;
    const int m = idx >> 11, col = idx & 2047;
    const int b = m >> 11, s = m & 2047;
    const unsigned short raw = Cqkv[(size_t)m * NQKV_ + col];
    if (col < 1792) {
        const int d = col & 127;
        const int dd = d & 63;
        const int axis = dd < 16 ? 0 : (dd < 40 ? 1 : 2);
        const size_t cidx = (((size_t)axis * B_ + b) * S_ + s) * HD_ + d;
        const int flg = flag[0];
        const float cs = flg ? ((const float*)cosp)[cidx] : bf2f(((const unsigned short*)cosp)[cidx]);
        const float sn = flg ? ((const float*)sinp)[cidx] : bf2f(((const unsigned short*)sinp)[cidx]);
        const float x  = bf2f(raw);
        const float xp = bf2f(Cqkv[(size_t)m * NQKV_ + (col ^ 64)]);
        float y = (d < 64) ? (x * cs - xp * sn) : (x * cs + xp * sn);
        if (col < 1536) {
            const int h = col >> 7;
            y *= 0.088388347648318447f;   // 1/sqrt(128) folded into Q
            Q[(((size_t)b * NH_ + h) * S_ + s) * HD_ + d] = f2bf(y);
        } else {
            const int kv = (col - 1536) >> 7;
            K[(((size_t)b * NKV_ + kv) * S_ + s) * HD_ + d] = f2bf(y);
        }
    } else {
        const int cv = col - 1792;
        const int kv = cv >> 7, d = cv & 127;
        Vt[(((size_t)b * NKV_ + kv) * HD_ + d) * S_ + s] = raw;
    }
}

// ---------------------------------------------------------------------------
// Flash attention, causal, q-tile 64 / k-tile 64, 4 waves x 16 q-rows.
// v3: double-buffered K/V staged via global_load_lds DMA (zero staging VGPRs
// -> no spill), linear LDS layouts with pre-swizzled global source
// (byte ^= (row&7)<<4) so ds_read_b128 stays at the bank floor. One barrier
// per tile (compiler's vmcnt(0) drain at s_barrier completes the DMA that
// flew under compute). Q in registers. LPT grid: qt descending via blockIdx.y.
// LDS = 2*16K (K) + 2*16K (V) + 9K (Ps) = 73 KiB -> 2 blocks/CU.
// ---------------------------------------------------------------------------
__global__ __launch_bounds__(256, 2) void attn_fwd(
    const unsigned short* __restrict__ Q,
    const unsigned short* __restrict__ K,
    const unsigned short* __restrict__ Vt,
    unsigned short* __restrict__ Aout)   // [4096, 1536]
{
    __shared__ unsigned short Ks2[2][64 * 128];   // linear, swizzled content
    __shared__ unsigned short Vs2[2][128 * 64];   // linear, swizzled content
    __shared__ unsigned short Ps[4][16][72];

    const int tid = threadIdx.x;
    const int w = tid >> 6, lane = tid & 63, quad = lane >> 4, l16 = lane & 15;
    const int bh = blockIdx.x;              // 0..23
    const int qt = 31 - blockIdx.y;         // heavy tiles dispatch first
    const int h  = bh % NH_;
    const int b  = bh / NH_;
    const int kvh = h / GRP_;
    const int q0 = qt * 64;

    const unsigned short* Qp = Q  + (((size_t)b * NH_ + h) * S_ + q0) * HD_;
    const char* Kg = (const char*)(K  + ((size_t)b * NKV_ + kvh) * S_ * HD_);
    const char* Vg = (const char*)(Vt + ((size_t)b * NKV_ + kvh) * HD_ * S_);

    // Q fragments straight to registers (each wave reads only its 16 rows)
    bf16x8 aq[4];
    {
        const unsigned short* qr = Qp + (size_t)(w * 16 + l16) * HD_ + quad * 8;
#pragma unroll
        for (int ks = 0; ks < 4; ks++)
            aq[ks] = *(const bf16x8*)(qr + ks * 32);
    }

    // Per-lane pre-swizzled source byte offsets for the DMA chunks.
    // K tile: 64 rows x 256 B (row-contiguous, tile stride 16384 B).
    // V tile: 128 rows x 128 B slice of [HD][S] (row stride 4096 B, tile step 128 B).
    int offK[4], offV[4];
#pragma unroll
    for (int i = 0; i < 4; i++) {
        const int cK = w * 4 + i;
        const int krow = cK * 4 + (lane >> 4);
        const int kc = (lane & 15) * 16;
        offK[i] = krow * 256 + (kc ^ ((krow & 7) << 4));
        const int cV = w * 4 + i;
        const int vrow = cV * 8 + (lane >> 3);
        const int vc = (lane & 7) * 16;
        offV[i] = vrow * 4096 + (vc ^ ((vrow & 7) << 4));
    }

#define STAGE(bufi, tt)                                                        \
    do {                                                                       \
        char* kd_ = (char*)&Ks2[bufi][0];                                      \
        char* vd_ = (char*)&Vs2[bufi][0];                                      \
        _Pragma("unroll")                                                      \
        for (int i_ = 0; i_ < 4; i_++)                                         \
            gload_lds16b(Kg + (tt) * 16384 + offK[i_],                         \
                         kd_ + (w * 4 + i_) * 1024);                           \
        _Pragma("unroll")                                                      \
        for (int i_ = 0; i_ < 4; i_++)                                         \
            gload_lds16b(Vg + (tt) * 128 + offV[i_],                           \
                         vd_ + (w * 4 + i_) * 1024);                           \
    } while (0)

    f32x4 O[8];
#pragma unroll
    for (int i = 0; i < 8; i++) O[i] = (f32x4)0.0f;
    float m_st[4] = {-1e30f, -1e30f, -1e30f, -1e30f};
    float l_st[4] = {0.f, 0.f, 0.f, 0.f};

    const int xorb = (l16 & 7) << 4;    // read-side swizzle (row&7 == l16&7)
    const int nkt = qt + 1;
    int cur = 0;

    STAGE(0, 0);
    __syncthreads();      // vmcnt(0) drain at barrier -> buf0 staged

    for (int t = 0; t < nkt; t++) {
        const int k0 = t * 64;
        if (t + 1 < nkt) STAGE(cur ^ 1, t + 1);    // DMA flies under compute

        const char* kb_ = (const char*)&Ks2[cur][0];
        const char* vb_ = (const char*)&Vs2[cur][0];

        f32x4 Sf[4];
#pragma unroll
        for (int i = 0; i < 4; i++) Sf[i] = (f32x4)0.0f;
        __builtin_amdgcn_s_setprio(1);
#pragma unroll
        for (int ks = 0; ks < 4; ks++) {
#pragma unroll
            for (int ni = 0; ni < 4; ni++) {
                bf16x8 bk = *(const bf16x8*)(kb_ + (ni * 16 + l16) * 256 +
                                             ((ks * 64 + quad * 16) ^ xorb));
                Sf[ni] = __builtin_amdgcn_mfma_f32_16x16x32_bf16(aq[ks], bk, Sf[ni], 0, 0, 0);
            }
        }
        __builtin_amdgcn_s_setprio(0);

        if (t == nkt - 1) {
#pragma unroll
            for (int ni = 0; ni < 4; ni++)
#pragma unroll
                for (int r = 0; r < 4; r++) {
                    const int kk = k0 + ni * 16 + l16;
                    const int qq = q0 + w * 16 + quad * 4 + r;
                    if (kk > qq) Sf[ni][r] = -1e9f;
                }
        }

        float alpha[4];
#pragma unroll
        for (int r = 0; r < 4; r++) {
            float mx = fmaxf(fmaxf(Sf[0][r], Sf[1][r]), fmaxf(Sf[2][r], Sf[3][r]));
#pragma unroll
            for (int sh = 1; sh < 16; sh <<= 1) mx = fmaxf(mx, __shfl_xor(mx, sh, 64));
            const float mn = fmaxf(m_st[r], mx);
            alpha[r] = __expf(m_st[r] - mn);
            m_st[r] = mn;
            float ps = 0.f;
#pragma unroll
            for (int ni = 0; ni < 4; ni++) {
                const float p = __expf(Sf[ni][r] - mn);
                Sf[ni][r] = p;
                ps += p;
            }
#pragma unroll
            for (int sh = 1; sh < 16; sh <<= 1) ps += __shfl_xor(ps, sh, 64);
            l_st[r] = l_st[r] * alpha[r] + ps;
        }
#pragma unroll
        for (int di = 0; di < 8; di++)
#pragma unroll
            for (int r = 0; r < 4; r++) O[di][r] *= alpha[r];

        // Ps is per-wave private: in-wave lgkm dependency only, no barrier.
#pragma unroll
        for (int ni = 0; ni < 4; ni++)
#pragma unroll
            for (int r = 0; r < 4; r++)
                Ps[w][quad * 4 + r][ni * 16 + l16] = f2bf(Sf[ni][r]);

        __builtin_amdgcn_s_setprio(1);
#pragma unroll
        for (int ks = 0; ks < 2; ks++) {
            bf16x8 ap = *(const bf16x8*)&Ps[w][l16][ks * 32 + quad * 8];
#pragma unroll
            for (int di = 0; di < 8; di++) {
                bf16x8 bv = *(const bf16x8*)(vb_ + (di * 16 + l16) * 128 +
                                             ((ks * 64 + quad * 16) ^ xorb));
                O[di] = __builtin_amdgcn_mfma_f32_16x16x32_bf16(ap, bv, O[di], 0, 0, 0);
            }
        }
        __builtin_amdgcn_s_setprio(0);

        __syncthreads();   // all reads of buf[cur] done + DMA for buf[cur^1] drained
        cur ^= 1;
    }
#undef STAGE

#pragma unroll
    for (int di = 0; di < 8; di++) {
        const int d = di * 16 + l16;
#pragma unroll
        for (int r = 0; r < 4; r++) {
            const int qrow = q0 + w * 16 + quad * 4 + r;
            const float v = O[di][r] / l_st[r];
            Aout[((size_t)b * S_ + qrow) * HID_ + h * HD_ + d] = f2bf(v);
        }
    }
}

extern "C" void kernel_launch(void* const* d_in, const int* in_sizes, int n_in,
                              void* d_out, int out_size, void* d_ws, size_t ws_size,
                              hipStream_t stream) {
    const void* hs   = d_in[0];
    const void* qw   = d_in[1];
    const void* qb   = d_in[2];
    const void* kw   = d_in[3];
    const void* kb   = d_in[4];
    const void* vw   = d_in[5];
    const void* vb   = d_in[6];
    const void* ow   = d_in[7];
    const void* cosp = d_in[8];
    const void* sinp = d_in[9];

    int* flag = (int*)d_ws;                                       // 16 shorts reserved
    unsigned short* conv = (unsigned short*)d_ws + 16;            // CV_TOT = 11796480
    unsigned short* Cqkv = conv + CV_TOT;                         // 8388608
    unsigned short* Qb   = Cqkv + (size_t)8388608;                // 6291456
    unsigned short* Kb   = Qb + (size_t)6291456;                  // 1048576
    unsigned short* Vtb  = Kb + (size_t)1048576;                  // 1048576
    unsigned short* Ao   = Cqkv;                                  // reuse (dead after rope)

    detect_dtype<<<1, 64, 0, stream>>>((const unsigned short*)hs, flag);
    convert_inputs<<<(CV_TOT / 8 + 255) / 256, 256, 0, stream>>>(hs, qw, kw, vw, ow, flag, conv);
    gemm_qkv<<<dim3(16, 32), 256, 0, stream>>>(conv + CV_HS, conv, qb, kb, vb, flag, Cqkv);
    rope_scatter<<<dim3((4096 * 2048) / 256), 256, 0, stream>>>(Cqkv, cosp, sinp, flag, Qb, Kb, Vtb);
    attn_fwd<<<dim3(24, 32), 256, 0, stream>>>(Qb, Kb, Vtb, Ao);
    gemm_o<<<dim3(12, 32), 256, 0, stream>>>(Ao, conv + CV_OW, flag, d_out);
}

// Round 4
// 345.739 us; speedup vs baseline: 1.4769x; 1.0044x over previous
//
#include <hip/hip_runtime.h>

// Problem constants
#define B_    2
#define S_    2048
#define HID_  1536
#define NH_   12
#define NKV_  2
#define HD_   128
#define GRP_  6
#define NQKV_ 2048

// converted-input region layout (element offsets)
#define CV_HS  0
#define CV_QW  6291456
#define CV_KW  8650752
#define CV_VW  9043968
#define CV_OW  9437184
#define CV_TOT 11796480

typedef __attribute__((ext_vector_type(8))) short bf16x8;
typedef __attribute__((ext_vector_type(4))) short bf16x4;
typedef __attribute__((ext_vector_type(4))) float f32x4;

__device__ __forceinline__ float bf2f(unsigned short u) {
    union { unsigned int i; float f; } v; v.i = ((unsigned int)u) << 16; return v.f;
}
__device__ __forceinline__ unsigned short f2bf(float f) {
    union { float f; unsigned int i; } v; v.f = f;
    unsigned int r = v.i + 0x7fffu + ((v.i >> 16) & 1u);  // RNE
    return (unsigned short)(r >> 16);
}

__device__ __forceinline__ void gload_lds16(const unsigned short* g, unsigned short* l) {
    __builtin_amdgcn_global_load_lds(
        (const __attribute__((address_space(1))) void*)g,
        (__attribute__((address_space(3))) void*)l, 16, 0, 0);
}
__device__ __forceinline__ void gload_lds16b(const char* g, char* l) {
    __builtin_amdgcn_global_load_lds(
        (const __attribute__((address_space(1))) void*)g,
        (__attribute__((address_space(3))) void*)l, 16, 0, 0);
}

// 16x16x16 bf16 MFMA (PV step): builtin name varies across ROCm versions.
#if __has_builtin(__builtin_amdgcn_mfma_f32_16x16x16bf16_1k)
__device__ __forceinline__ f32x4 mfma16(bf16x4 a, bf16x4 b, f32x4 c) {
    return __builtin_amdgcn_mfma_f32_16x16x16bf16_1k(a, b, c, 0, 0, 0);
}
#elif __has_builtin(__builtin_amdgcn_mfma_f32_16x16x16_bf16)
__device__ __forceinline__ f32x4 mfma16(bf16x4 a, bf16x4 b, f32x4 c) {
    return __builtin_amdgcn_mfma_f32_16x16x16_bf16(a, b, c, 0, 0, 0);
}
#else
__device__ __forceinline__ f32x4 mfma16(bf16x4 a, bf16x4 b, f32x4 c) {
    asm volatile("v_mfma_f32_16x16x16_bf16 %0, %1, %2, %0"
                 : "+v"(c) : "v"(a), "v"(b));
    return c;
}
#endif

// ---------------------------------------------------------------------------
// dtype detection: if hidden_states is bf16, even-indexed ushorts are bf16
// values of N(0,1) data (exponent byte near 127). flag: 0 = bf16, 1 = f32.
// ---------------------------------------------------------------------------
__global__ void detect_dtype(const unsigned short* __restrict__ hs, int* __restrict__ flag) {
    const int i = threadIdx.x;                  // 64 threads
    const unsigned short u = hs[2 * i];
    const int e = (u >> 7) & 0xFF;
    const bool sane = (e >= 96 && e <= 143);    // |x| in [2^-31, 2^16]
    const unsigned long long m = __ballot(sane);
    if (i == 0) flag[0] = (__popcll(m) < 32) ? 1 : 0;
}

// 8 elements per thread; all region boundaries are multiples of 8.
__global__ __launch_bounds__(256) void convert_inputs(
    const void* __restrict__ hs, const void* __restrict__ qw,
    const void* __restrict__ kw, const void* __restrict__ vw,
    const void* __restrict__ ow, const int* __restrict__ flag,
    unsigned short* __restrict__ dst)
{
    const size_t idx = ((size_t)blockIdx.x * 256 + threadIdx.x) * 8;
    if (idx >= CV_TOT) return;
    const void* p; size_t j;
    if (idx < CV_QW)      { p = hs; j = idx; }
    else if (idx < CV_KW) { p = qw; j = idx - CV_QW; }
    else if (idx < CV_VW) { p = kw; j = idx - CV_KW; }
    else if (idx < CV_OW) { p = vw; j = idx - CV_VW; }
    else                  { p = ow; j = idx - CV_OW; }
    if (flag[0]) {
        const float* src = (const float*)p + j;
        const float4 f0 = *(const float4*)(src);
        const float4 f1 = *(const float4*)(src + 4);
        uint4 o;
        o.x = (unsigned int)f2bf(f0.x) | ((unsigned int)f2bf(f0.y) << 16);
        o.y = (unsigned int)f2bf(f0.z) | ((unsigned int)f2bf(f0.w) << 16);
        o.z = (unsigned int)f2bf(f1.x) | ((unsigned int)f2bf(f1.y) << 16);
        o.w = (unsigned int)f2bf(f1.z) | ((unsigned int)f2bf(f1.w) << 16);
        *(uint4*)(dst + idx) = o;
    } else {
        *(uint4*)(dst + idx) = *(const uint4*)((const unsigned short*)p + j);
    }
}

// ---------------------------------------------------------------------------
// GEMM QKV: C[m,n] = sum_k A[m,k]*W[n,k] + bias. m97 structure.
// ---------------------------------------------------------------------------
__global__ __launch_bounds__(256) void gemm_qkv(
    const unsigned short* __restrict__ A,     // bf16 hidden [4096,1536]
    const unsigned short* __restrict__ Wall,  // bf16 region base (qw/kw/vw)
    const void* __restrict__ qb, const void* __restrict__ kb,
    const void* __restrict__ vb, const int* __restrict__ flag,
    unsigned short* __restrict__ C)           // [4096,2048] bf16
{
    __shared__ unsigned short As[128 * 32];
    __shared__ unsigned short Ws[128 * 32];
    const int tid = threadIdx.x;
    const int w = tid >> 6, lane = tid & 63, quad = lane >> 4, l16 = lane & 15;
    const int wr = w >> 1, wc = w & 1;
    const int n0 = blockIdx.x * 128;
    const int m0 = blockIdx.y * 128;
    const int flg = flag[0];

    const unsigned short* Wp; const void* bias; int boff;
    if (n0 < 1536)      { Wp = Wall + CV_QW + (size_t)n0 * HID_;          bias = qb; boff = n0; }
    else if (n0 < 1792) { Wp = Wall + CV_KW + (size_t)(n0 - 1536) * HID_; bias = kb; boff = n0 - 1536; }
    else                { Wp = Wall + CV_VW + (size_t)(n0 - 1792) * HID_; bias = vb; boff = n0 - 1792; }

    f32x4 acc[4][4];
#pragma unroll
    for (int i = 0; i < 4; i++)
#pragma unroll
        for (int j = 0; j < 4; j++) acc[i][j] = (f32x4)0.0f;

    const int c0 = w * 64, c1 = 256 + w * 64;
    const int ca = c0 + lane, cb = c1 + lane;
    const int rA0 = ca >> 2, pA0 = (ca & 3) * 8;
    const int rA1 = cb >> 2, pA1 = (cb & 3) * 8;

    for (int kt = 0; kt < HID_ / 32; ++kt) {
        const int k0 = kt * 32;
        __syncthreads();
        gload_lds16(A  + (size_t)(m0 + rA0) * HID_ + k0 + pA0, &As[c0 * 8]);
        gload_lds16(A  + (size_t)(m0 + rA1) * HID_ + k0 + pA1, &As[c1 * 8]);
        gload_lds16(Wp + (size_t)rA0 * HID_ + k0 + pA0, &Ws[c0 * 8]);
        gload_lds16(Wp + (size_t)rA1 * HID_ + k0 + pA1, &Ws[c1 * 8]);
        __syncthreads();

        bf16x8 a[4], b[4];
#pragma unroll
        for (int mi = 0; mi < 4; mi++)
            a[mi] = *(const bf16x8*)&As[(wr * 64 + mi * 16 + l16) * 32 + quad * 8];
#pragma unroll
        for (int ni = 0; ni < 4; ni++)
            b[ni] = *(const bf16x8*)&Ws[(wc * 64 + ni * 16 + l16) * 32 + quad * 8];
#pragma unroll
        for (int mi = 0; mi < 4; mi++)
#pragma unroll
            for (int ni = 0; ni < 4; ni++)
                acc[mi][ni] = __builtin_amdgcn_mfma_f32_16x16x32_bf16(a[mi], b[ni], acc[mi][ni], 0, 0, 0);
    }

#pragma unroll
    for (int mi = 0; mi < 4; mi++) {
        const int row = m0 + wr * 64 + mi * 16 + quad * 4;
#pragma unroll
        for (int ni = 0; ni < 4; ni++) {
            const int cl = wc * 64 + ni * 16 + l16;
            const float bv = flg ? ((const float*)bias)[boff + cl]
                                 : bf2f(((const unsigned short*)bias)[boff + cl]);
#pragma unroll
            for (int r = 0; r < 4; r++)
                C[(size_t)(row + r) * NQKV_ + n0 + cl] = f2bf(acc[mi][ni][r] + bv);
        }
    }
}

__global__ __launch_bounds__(256) void gemm_o(
    const unsigned short* __restrict__ A,   // attn_out [4096,1536] bf16
    const unsigned short* __restrict__ W,   // o_w bf16 [1536,1536]
    const int* __restrict__ flag,
    void* __restrict__ C)                   // out [4096,1536] bf16 or f32
{
    __shared__ unsigned short As[128 * 32];
    __shared__ unsigned short Ws[128 * 32];
    const int tid = threadIdx.x;
    const int w = tid >> 6, lane = tid & 63, quad = lane >> 4, l16 = lane & 15;
    const int wr = w >> 1, wc = w & 1;
    const int n0 = blockIdx.x * 128;
    const int m0 = blockIdx.y * 128;
    const int flg = flag[0];
    const unsigned short* Wp = W + (size_t)n0 * HID_;

    f32x4 acc[4][4];
#pragma unroll
    for (int i = 0; i < 4; i++)
#pragma unroll
        for (int j = 0; j < 4; j++) acc[i][j] = (f32x4)0.0f;

    const int c0 = w * 64, c1 = 256 + w * 64;
    const int ca = c0 + lane, cb = c1 + lane;
    const int rA0 = ca >> 2, pA0 = (ca & 3) * 8;
    const int rA1 = cb >> 2, pA1 = (cb & 3) * 8;

    for (int kt = 0; kt < HID_ / 32; ++kt) {
        const int k0 = kt * 32;
        __syncthreads();
        gload_lds16(A  + (size_t)(m0 + rA0) * HID_ + k0 + pA0, &As[c0 * 8]);
        gload_lds16(A  + (size_t)(m0 + rA1) * HID_ + k0 + pA1, &As[c1 * 8]);
        gload_lds16(Wp + (size_t)rA0 * HID_ + k0 + pA0, &Ws[c0 * 8]);
        gload_lds16(Wp + (size_t)rA1 * HID_ + k0 + pA1, &Ws[c1 * 8]);
        __syncthreads();

        bf16x8 a[4], b[4];
#pragma unroll
        for (int mi = 0; mi < 4; mi++)
            a[mi] = *(const bf16x8*)&As[(wr * 64 + mi * 16 + l16) * 32 + quad * 8];
#pragma unroll
        for (int ni = 0; ni < 4; ni++)
            b[ni] = *(const bf16x8*)&Ws[(wc * 64 + ni * 16 + l16) * 32 + quad * 8];
#pragma unroll
        for (int mi = 0; mi < 4; mi++)
#pragma unroll
            for (int ni = 0; ni < 4; ni++)
                acc[mi][ni] = __builtin_amdgcn_mfma_f32_16x16x32_bf16(a[mi], b[ni], acc[mi][ni], 0, 0, 0);
    }

#pragma unroll
    for (int mi = 0; mi < 4; mi++) {
        const int row = m0 + wr * 64 + mi * 16 + quad * 4;
#pragma unroll
        for (int ni = 0; ni < 4; ni++) {
            const int col = n0 + wc * 64 + ni * 16 + l16;
#pragma unroll
            for (int r = 0; r < 4; r++) {
                const size_t off = (size_t)(row + r) * HID_ + col;
                if (flg) ((float*)C)[off] = acc[mi][ni][r];
                else ((unsigned short*)C)[off] = f2bf(acc[mi][ni][r]);
            }
        }
    }
}

// ---------------------------------------------------------------------------
// mrope + scatter (cos/sin read flag-adaptively from original inputs)
// Q is scaled by 1/sqrt(128) * log2(e): attention uses exp2-domain softmax.
// ---------------------------------------------------------------------------
__global__ __launch_bounds__(256) void rope_scatter(
    const unsigned short* __restrict__ Cqkv,
    const void* __restrict__ cosp, const void* __restrict__ sinp,
    const int* __restrict__ flag,
    unsigned short* __restrict__ Q,           // [B,NH,S,HD]
    unsigned short* __restrict__ K,           // [B,NKV,S,HD]
    unsigned short* __restrict__ Vt)          // [B,NKV,HD,S]
{
    const int idx = blockIdx.x * 256 + threadIdx.x;
    const int m = idx >> 11, col = idx & 2047;
    const int b = m >> 11, s = m & 2047;
    const unsigned short raw = Cqkv[(size_t)m * NQKV_ + col];
    if (col < 1792) {
        const int d = col & 127;
        const int dd = d & 63;
        const int axis = dd < 16 ? 0 : (dd < 40 ? 1 : 2);
        const size_t cidx = (((size_t)axis * B_ + b) * S_ + s) * HD_ + d;
        const int flg = flag[0];
        const float cs = flg ? ((const float*)cosp)[cidx] : bf2f(((const unsigned short*)cosp)[cidx]);
        const float sn = flg ? ((const float*)sinp)[cidx] : bf2f(((const unsigned short*)sinp)[cidx]);
        const float x  = bf2f(raw);
        const float xp = bf2f(Cqkv[(size_t)m * NQKV_ + (col ^ 64)]);
        float y = (d < 64) ? (x * cs - xp * sn) : (x * cs + xp * sn);
        if (col < 1536) {
            const int h = col >> 7;
            y *= 0.1275174313431108f;   // 1/sqrt(128) * log2(e) folded into Q
            Q[(((size_t)b * NH_ + h) * S_ + s) * HD_ + d] = f2bf(y);
        } else {
            const int kv = (col - 1536) >> 7;
            K[(((size_t)b * NKV_ + kv) * S_ + s) * HD_ + d] = f2bf(y);
        }
    } else {
        const int cv = col - 1792;
        const int kv = cv >> 7, d = cv & 127;
        Vt[(((size_t)b * NKV_ + kv) * HD_ + d) * S_ + s] = raw;
    }
}

// ---------------------------------------------------------------------------
// Flash attention v4, causal, q-tile 64 / k-tile 64, 4 waves x 16 q-rows.
// Swapped QK^T (S^T = mfma(K,Q)): each lane owns q-row = l16 -> lane-local
// softmax (2 shuffles/tile instead of 32); PV via mfma_16x16x16 with P^T
// fed directly from the S^T C-fragment (B-layout k=quad*4+j matches exactly)
// -> no Ps LDS bounce. K double-buffered + V single-buffered via
// global_load_lds DMA with pre-swizzled source: LDS = 49152 B -> 3 blocks/CU
// (768 blocks = full residency). Two barriers/tile. exp2-domain softmax.
// ---------------------------------------------------------------------------
__global__ __launch_bounds__(256, 3) void attn_fwd(
    const unsigned short* __restrict__ Q,
    const unsigned short* __restrict__ K,
    const unsigned short* __restrict__ Vt,
    unsigned short* __restrict__ Aout)   // [4096, 1536]
{
    __shared__ unsigned short Ks2[2][64 * 128];   // linear, swizzled content
    __shared__ unsigned short Vs1[128 * 64];      // linear, swizzled content

    const int tid = threadIdx.x;
    const int w = tid >> 6, lane = tid & 63, quad = lane >> 4, l16 = lane & 15;
    const int bh = blockIdx.x;              // 0..23
    const int qt = 31 - blockIdx.y;         // heavy tiles dispatch first
    const int h  = bh % NH_;
    const int b  = bh / NH_;
    const int kvh = h / GRP_;
    const int q0 = qt * 64;

    const unsigned short* Qp = Q  + (((size_t)b * NH_ + h) * S_ + q0) * HD_;
    const char* Kg = (const char*)(K  + ((size_t)b * NKV_ + kvh) * S_ * HD_);
    const char* Vg = (const char*)(Vt + ((size_t)b * NKV_ + kvh) * HD_ * S_);

    // Q fragments in registers: row q = l16, k-chunk quad*8 (B-operand of QK^T)
    bf16x8 aq[4];
    {
        const unsigned short* qr = Qp + (size_t)(w * 16 + l16) * HD_ + quad * 8;
#pragma unroll
        for (int ks = 0; ks < 4; ks++)
            aq[ks] = *(const bf16x8*)(qr + ks * 32);
    }

    // Per-lane pre-swizzled source byte offsets for the DMA chunks.
    int offK[4], offV[4];
#pragma unroll
    for (int i = 0; i < 4; i++) {
        const int cK = w * 4 + i;
        const int krow = cK * 4 + (lane >> 4);
        const int kc = (lane & 15) * 16;
        offK[i] = krow * 256 + (kc ^ ((krow & 7) << 4));
        const int cV = w * 4 + i;
        const int vrow = cV * 8 + (lane >> 3);
        const int vc = (lane & 7) * 16;
        offV[i] = vrow * 4096 + (vc ^ ((vrow & 7) << 4));
    }

#define STAGE_K(bufi, tt)                                                      \
    do {                                                                       \
        char* kd_ = (char*)&Ks2[bufi][0];                                      \
        _Pragma("unroll")                                                      \
        for (int i_ = 0; i_ < 4; i_++)                                         \
            gload_lds16b(Kg + (tt) * 16384 + offK[i_],                         \
                         kd_ + (w * 4 + i_) * 1024);                           \
    } while (0)
#define STAGE_V(tt)                                                            \
    do {                                                                       \
        char* vd_ = (char*)&Vs1[0];                                            \
        _Pragma("unroll")                                                      \
        for (int i_ = 0; i_ < 4; i_++)                                         \
            gload_lds16b(Vg + (tt) * 128 + offV[i_],                           \
                         vd_ + (w * 4 + i_) * 1024);                           \
    } while (0)

    f32x4 Ot[8];                         // O^T fragments: row d, col q=l16
#pragma unroll
    for (int i = 0; i < 8; i++) Ot[i] = (f32x4)0.0f;
    float m_st = -1e30f, l_st = 0.f;     // lane-local (q = l16)

    const int xorb = (l16 & 7) << 4;     // read-side swizzle (row&7 == l16&7)
    const int nkt = qt + 1;
    int cur = 0;

    STAGE_K(0, 0);
    __syncthreads();      // vmcnt(0) drain at barrier -> K0 staged

    for (int t = 0; t < nkt; t++) {
        const int k0 = t * 64;
        STAGE_V(t);                                // lands at B1
        if (t + 1 < nkt) STAGE_K(cur ^ 1, t + 1);  // lands at B1 (early, ok)

        const char* kb_ = (const char*)&Ks2[cur][0];

        // S^T = K * Q^T : rows k (A = K-frag), cols q (B = Q-frag).
        f32x4 Sf[4];
#pragma unroll
        for (int i = 0; i < 4; i++) Sf[i] = (f32x4)0.0f;
        __builtin_amdgcn_s_setprio(1);
#pragma unroll
        for (int ks = 0; ks < 4; ks++) {
#pragma unroll
            for (int ni = 0; ni < 4; ni++) {
                bf16x8 bk = *(const bf16x8*)(kb_ + (ni * 16 + l16) * 256 +
                                             ((ks * 64 + quad * 16) ^ xorb));
                Sf[ni] = __builtin_amdgcn_mfma_f32_16x16x32_bf16(bk, aq[ks], Sf[ni], 0, 0, 0);
            }
        }
        __builtin_amdgcn_s_setprio(0);

        // causal mask: k index = k0 + ni*16 + quad*4 + r, q index = q0 + w*16 + l16
        if (t == nkt - 1) {
            const int qq = q0 + w * 16 + l16;
#pragma unroll
            for (int ni = 0; ni < 4; ni++)
#pragma unroll
                for (int r = 0; r < 4; r++) {
                    const int kk = k0 + ni * 16 + quad * 4 + r;
                    if (kk > qq) Sf[ni][r] = -1e9f;
                }
        }

        // lane-local online softmax (exp2 domain; log2e folded into Q)
        float mx = Sf[0][0];
#pragma unroll
        for (int ni = 0; ni < 4; ni++)
#pragma unroll
            for (int r = 0; r < 4; r++) mx = fmaxf(mx, Sf[ni][r]);
        mx = fmaxf(mx, __shfl_xor(mx, 16, 64));
        mx = fmaxf(mx, __shfl_xor(mx, 32, 64));
        const float mn = fmaxf(m_st, mx);
        const float alpha = exp2f(m_st - mn);
        m_st = mn;
        float ps = 0.f;
#pragma unroll
        for (int ni = 0; ni < 4; ni++)
#pragma unroll
            for (int r = 0; r < 4; r++) {
                const float p = exp2f(Sf[ni][r] - mn);
                Sf[ni][r] = p;
                ps += p;
            }
        ps += __shfl_xor(ps, 16, 64);
        ps += __shfl_xor(ps, 32, 64);
        l_st = l_st * alpha + ps;
#pragma unroll
        for (int di = 0; di < 8; di++)
#pragma unroll
            for (int r = 0; r < 4; r++) Ot[di][r] *= alpha;

        __syncthreads();   // B1: V[t] (and K[t+1]) landed

        // O^T += V^T * P^T  (A = V^T-frag from LDS, B = P^T from S^T C-frag)
        const char* vb_ = (const char*)&Vs1[0];
        __builtin_amdgcn_s_setprio(1);
#pragma unroll
        for (int ni = 0; ni < 4; ni++) {
            bf16x4 pa;
            pa[0] = (short)f2bf(Sf[ni][0]);
            pa[1] = (short)f2bf(Sf[ni][1]);
            pa[2] = (short)f2bf(Sf[ni][2]);
            pa[3] = (short)f2bf(Sf[ni][3]);
#pragma unroll
            for (int di = 0; di < 8; di++) {
                bf16x4 va = *(const bf16x4*)(vb_ + (di * 16 + l16) * 128 +
                                             ((ni * 32 + quad * 8) ^ xorb));
                Ot[di] = mfma16(va, pa, Ot[di]);
            }
        }
        __builtin_amdgcn_s_setprio(0);

        __syncthreads();   // B2: all Vs reads done before next STAGE_V
        cur ^= 1;
    }
#undef STAGE_K
#undef STAGE_V

    // Ot[di][r]: d = di*16 + quad*4 + r, q = l16 (l_st lane-local)
    const float rl = 1.0f / l_st;
    const int qrow = q0 + w * 16 + l16;
    unsigned short* dst = Aout + ((size_t)b * S_ + qrow) * HID_ + h * HD_;
#pragma unroll
    for (int di = 0; di < 8; di++) {
        ushort4 o;
        o.x = f2bf(Ot[di][0] * rl);
        o.y = f2bf(Ot[di][1] * rl);
        o.z = f2bf(Ot[di][2] * rl);
        o.w = f2bf(Ot[di][3] * rl);
        *(ushort4*)(dst + di * 16 + quad * 4) = o;
    }
}

extern "C" void kernel_launch(void* const* d_in, const int* in_sizes, int n_in,
                              void* d_out, int out_size, void* d_ws, size_t ws_size,
                              hipStream_t stream) {
    const void* hs   = d_in[0];
    const void* qw   = d_in[1];
    const void* qb   = d_in[2];
    const void* kw   = d_in[3];
    const void* kb   = d_in[4];
    const void* vw   = d_in[5];
    const void* vb   = d_in[6];
    const void* ow   = d_in[7];
    const void* cosp = d_in[8];
    const void* sinp = d_in[9];

    int* flag = (int*)d_ws;                                       // 16 shorts reserved
    unsigned short* conv = (unsigned short*)d_ws + 16;            // CV_TOT = 11796480
    unsigned short* Cqkv = conv + CV_TOT;                         // 8388608
    unsigned short* Qb   = Cqkv + (size_t)8388608;                // 6291456
    unsigned short* Kb   = Qb + (size_t)6291456;                  // 1048576
    unsigned short* Vtb  = Kb + (size_t)1048576;                  // 1048576
    unsigned short* Ao   = Cqkv;                                  // reuse (dead after rope)

    detect_dtype<<<1, 64, 0, stream>>>((const unsigned short*)hs, flag);
    convert_inputs<<<(CV_TOT / 8 + 255) / 256, 256, 0, stream>>>(hs, qw, kw, vw, ow, flag, conv);
    gemm_qkv<<<dim3(16, 32), 256, 0, stream>>>(conv + CV_HS, conv, qb, kb, vb, flag, Cqkv);
    rope_scatter<<<dim3((4096 * 2048) / 256), 256, 0, stream>>>(Cqkv, cosp, sinp, flag, Qb, Kb, Vtb);
    attn_fwd<<<dim3(24, 32), 256, 0, stream>>>(Qb, Kb, Vtb, Ao);
    gemm_o<<<dim3(12, 32), 256, 0, stream>>>(Ao, conv + CV_OW, flag, d_out);
}